// Round 9
// baseline (249.134 us; speedup 1.0000x reference)
//
#include <hip/hip_runtime.h>
#include <math.h>

#define HD     64
#define NPIX   9216
#define B4     4
#define K9     9
#define KT     128           // keys per LDS tile
#define ZS     8             // key-split factor (gate)
#define KQZ    (NPIX / ZS)   // 1152 keys per gate block
#define NTZ    (KQZ / KT)    // 9 tiles
#define SSL    2             // sample slices (tau from keys 0..2303)
#define DGATE  13.0f         // gate margin (scaled-score units)
#define THRM   4.5f          // exact-rescore margin (mfma + pack rounding)
#define CAP    96            // candidate slots per query

typedef __attribute__((ext_vector_type(8))) short bf16x8;
typedef __attribute__((ext_vector_type(4))) float f32x4;
typedef unsigned short ushort_t;

__device__ __forceinline__ ushort_t f2bf(float x) {
  unsigned u = __float_as_uint(x);
  unsigned r = (u + 0x7fffu + ((u >> 16) & 1u)) >> 16;   // RNE
  return (ushort_t)r;
}
// monotone bf16-bits -> 16-bit sortable key
__device__ __forceinline__ unsigned bfkey(ushort_t b) {
  return (b & 0x8000u) ? ((~(unsigned)b) & 0xFFFFu) : ((unsigned)b | 0x8000u);
}

// ---- prep: transpose [b][d][n] -> [b][n][d]; z=0: Qbf(x8); z=1: Kbf+Kt; z=2: Vt
__global__ __launch_bounds__(256) void prep_kernel(
    const float* __restrict__ qg, const float* __restrict__ kg,
    const float* __restrict__ vg,
    ushort_t* __restrict__ Qbf, ushort_t* __restrict__ Kbf,
    float* __restrict__ Kt, float* __restrict__ Vt) {
  __shared__ float Ts[64][65];
  const int b = blockIdx.y, n0 = blockIdx.x * 64, z = blockIdx.z;
  const float* src = (z == 0) ? qg : (z == 1) ? kg : vg;
  const int tid = threadIdx.x;
  #pragma unroll
  for (int i = 0; i < 16; ++i) {
    const int idx = i * 256 + tid, c = idx >> 6, nl = idx & 63;
    Ts[c][nl] = src[((size_t)b * HD + c) * NPIX + n0 + nl];
  }
  __syncthreads();
  if (z == 0) {
    #pragma unroll
    for (int i = 0; i < 16; ++i) {
      const int idx = i * 256 + tid, nl = idx >> 6, d = idx & 63;
      Qbf[((size_t)b * NPIX + n0 + nl) * HD + d] = f2bf(Ts[d][nl] * 8.f);
    }
  } else if (z == 1) {
    #pragma unroll
    for (int i = 0; i < 16; ++i) {
      const int idx = i * 256 + tid, nl = idx >> 6, d = idx & 63;
      const float x = Ts[d][nl];
      const size_t o = ((size_t)b * NPIX + n0 + nl) * HD + d;
      Kbf[o] = f2bf(x); Kt[o] = x;
    }
  } else {
    #pragma unroll
    for (int i = 0; i < 16; ++i) {
      const int idx = i * 256 + tid, nl = idx >> 6, d = idx & 63;
      Vt[((size_t)b * NPIX + n0 + nl) * HD + d] = Ts[d][nl];
    }
  }
}

// ---------------- async global -> LDS (16B per lane, linear dest) ------------
__device__ __forceinline__ void gl_lds16(const void* g, void* l) {
  auto gp = reinterpret_cast<const unsigned int __attribute__((address_space(1)))*>(
      reinterpret_cast<uintptr_t>(g));
  auto lp = reinterpret_cast<unsigned int __attribute__((address_space(3)))*>(
      reinterpret_cast<uintptr_t>(l));
  __builtin_amdgcn_global_load_lds(gp, lp, 16, 0, 0);
}

// ---- sorted-9 insert, float with (val desc, idx asc) tie-break --------------
__device__ __forceinline__ void ins9t(float (&tv)[K9], int (&ti)[K9], float s, int m) {
  float cv = s; int ci = m;
  #pragma unroll
  for (int r = 0; r < K9; ++r) {
    const bool c = (cv > tv[r]) || (cv == tv[r] && ci < ti[r]);
    const float hv = c ? cv : tv[r];  const float lv = c ? tv[r] : cv;
    const int   hk = c ? ci : ti[r];  const int   lk = c ? ti[r] : ci;
    tv[r] = hv; ti[r] = hk; cv = lv; ci = lk;
  }
}
// ---- sorted-9 insert, packed uint (strict >, packed encodes idx order) ------
__device__ __forceinline__ void ins9p(unsigned (&tv)[K9], unsigned p) {
  unsigned cv = p;
  #pragma unroll
  for (int r = 0; r < K9; ++r) {
    const bool c = cv > tv[r];
    const unsigned hv = c ? cv : tv[r]; const unsigned lv = c ? tv[r] : cv;
    tv[r] = hv; cv = lv;
  }
}

// ==== sample: per-query max over keys [z*1152, (z+1)*1152), 64 q/wave ========
__global__ __launch_bounds__(256, 4) void pass_sample(
    const ushort_t* __restrict__ Qbf, const ushort_t* __restrict__ Kbf,
    float* __restrict__ Pm) {
  __shared__ __align__(16) char SM[2][16384];

  const int tid = threadIdx.x;
  const int w = tid >> 6, l = tid & 63, lg = l >> 4, lc = l & 15;
  const int b = blockIdx.y, qbase = blockIdx.x * 256, z = blockIdx.z;
  const int kbase = z * KQZ;
  const int qw = qbase + w * 64;

  bf16x8 qf[4][2];
  #pragma unroll
  for (int c = 0; c < 4; ++c) {
    const size_t qr = ((size_t)b * NPIX + qw + c * 16 + lc) * HD + lg * 8;
    qf[c][0] = *reinterpret_cast<const bf16x8*>(Qbf + qr);
    qf[c][1] = *reinterpret_cast<const bf16x8*>(Qbf + qr + 32);
  }

  const char* kB = reinterpret_cast<const char*>(Kbf + (size_t)b * NPIX * HD);
  const int sr = tid >> 3, sc = tid & 7;
  const int srcoff = sr * 128 + ((sc ^ (sr & 7)) << 4);
  const int hdst = w * 1024;
  const int o0 = ((lg ^ (lc & 7)) << 4);
  const int o1 = (((4 + lg) ^ (lc & 7)) << 4);

  auto stage = [&](int tile, int nb) {
    const size_t toff = ((size_t)(kbase + tile * KT)) * 128 + srcoff;
    #pragma unroll
    for (int p = 0; p < 4; ++p)
      gl_lds16(kB + toff + p * 4096, SM[nb] + p * 4096 + hdst);
  };

  float m[4];
  #pragma unroll
  for (int c = 0; c < 4; ++c) m[c] = -3.4e38f;

  stage(0, 0);
  __syncthreads();

  for (int t = 0; t < NTZ; ++t) {
    const int cur = t & 1;
    if (t + 1 < NTZ) stage(t + 1, cur ^ 1);
    const char* kt = SM[cur];
    #pragma unroll
    for (int s = 0; s < 8; ++s) {
      const int ro = (s * 16 + lc) * 128;
      const bf16x8 ah0 = *reinterpret_cast<const bf16x8*>(kt + ro + o0);
      const bf16x8 ah1 = *reinterpret_cast<const bf16x8*>(kt + ro + o1);
      #pragma unroll
      for (int c = 0; c < 4; ++c) {
        f32x4 acc = {0.f, 0.f, 0.f, 0.f};
        acc = __builtin_amdgcn_mfma_f32_16x16x32_bf16(ah0, qf[c][0], acc, 0, 0, 0);
        acc = __builtin_amdgcn_mfma_f32_16x16x32_bf16(ah1, qf[c][1], acc, 0, 0, 0);
        m[c] = fmaxf(m[c], fmaxf(fmaxf(acc[0], acc[1]), fmaxf(acc[2], acc[3])));
      }
    }
    __syncthreads();
  }

  // combine the 4 lane-groups once at the end
  #pragma unroll
  for (int c = 0; c < 4; ++c) {
    m[c] = fmaxf(m[c], __shfl_xor(m[c], 16, 64));
    m[c] = fmaxf(m[c], __shfl_xor(m[c], 32, 64));
  }
  if (lg == 0) {
    #pragma unroll
    for (int c = 0; c < 4; ++c)
      Pm[((size_t)b * NPIX + qw + c * 16 + lc) * SSL + z] = m[c];
  }
}

// ==== gate: hi-only scores, per-lane tau-seeded gate, packed append ==========
__global__ __launch_bounds__(256, 4) void pass_gate(
    const ushort_t* __restrict__ Qbf, const ushort_t* __restrict__ Kbf,
    const float* __restrict__ Pm,
    int* __restrict__ Cnt, unsigned* __restrict__ Cand) {
  __shared__ __align__(16) char SM[2][16384];

  const int tid = threadIdx.x;
  const int w = tid >> 6, l = tid & 63, lg = l >> 4, lc = l & 15;
  const int b = blockIdx.y, qbase = blockIdx.x * 256, z = blockIdx.z;
  const int kbase = z * KQZ;
  const int qw = qbase + w * 64;

  bf16x8 qf[4][2];
  int qi[4];
  float gt[4];
  #pragma unroll
  for (int c = 0; c < 4; ++c) {
    qi[c] = b * NPIX + qw + c * 16 + lc;
    const size_t qr = (size_t)qi[c] * HD + lg * 8;
    qf[c][0] = *reinterpret_cast<const bf16x8*>(Qbf + qr);
    qf[c][1] = *reinterpret_cast<const bf16x8*>(Qbf + qr + 32);
    gt[c] = fmaxf(Pm[(size_t)qi[c] * SSL], Pm[(size_t)qi[c] * SSL + 1]) - DGATE;
  }

  const char* kB = reinterpret_cast<const char*>(Kbf + (size_t)b * NPIX * HD);
  const int sr = tid >> 3, sc = tid & 7;
  const int srcoff = sr * 128 + ((sc ^ (sr & 7)) << 4);
  const int hdst = w * 1024;
  const int o0 = ((lg ^ (lc & 7)) << 4);
  const int o1 = (((4 + lg) ^ (lc & 7)) << 4);

  auto stage = [&](int tile, int nb) {
    const size_t toff = ((size_t)(kbase + tile * KT)) * 128 + srcoff;
    #pragma unroll
    for (int p = 0; p < 4; ++p)
      gl_lds16(kB + toff + p * 4096, SM[nb] + p * 4096 + hdst);
  };

  auto emit = [&](float s, int key, int qq) {
    const int slot = atomicAdd(&Cnt[qq], 1);
    if (slot < CAP)
      Cand[(size_t)qq * CAP + slot] =
          (bfkey(f2bf(s)) << 16) | (unsigned)(0xFFFF - key);
  };

  stage(0, 0);
  __syncthreads();

  for (int t = 0; t < NTZ; ++t) {
    const int cur = t & 1;
    if (t + 1 < NTZ) stage(t + 1, cur ^ 1);
    const char* kt = SM[cur];

    #pragma unroll
    for (int s = 0; s < 8; ++s) {
      const int ro = (s * 16 + lc) * 128;
      const bf16x8 ah0 = *reinterpret_cast<const bf16x8*>(kt + ro + o0);
      const bf16x8 ah1 = *reinterpret_cast<const bf16x8*>(kt + ro + o1);
      f32x4 acc[4];
      #pragma unroll
      for (int c = 0; c < 4; ++c) {
        f32x4 a = {0.f, 0.f, 0.f, 0.f};
        a = __builtin_amdgcn_mfma_f32_16x16x32_bf16(ah0, qf[c][0], a, 0, 0, 0);
        a = __builtin_amdgcn_mfma_f32_16x16x32_bf16(ah1, qf[c][1], a, 0, 0, 0);
        acc[c] = a;
      }
      const int kb = kbase + t * KT + s * 16 + lg * 4;  // C/D: row=(lane>>4)*4+reg
      #pragma unroll
      for (int c = 0; c < 4; ++c) {
        const float s4 = fmaxf(fmaxf(acc[c][0], acc[c][1]),
                               fmaxf(acc[c][2], acc[c][3]));
        const float old = gt[c];
        gt[c] = fmaxf(old, s4 - DGATE);         // per-lane running tighten
        if (s4 > old) {                          // rare
          if (acc[c][0] > gt[c]) emit(acc[c][0], kb,     qi[c]);
          if (acc[c][1] > gt[c]) emit(acc[c][1], kb + 1, qi[c]);
          if (acc[c][2] > gt[c]) emit(acc[c][2], kb + 2, qi[c]);
          if (acc[c][3] > gt[c]) emit(acc[c][3], kb + 3, qi[c]);
        }
      }
    }
    __syncthreads();
  }
}

// ==== merge: top-9 by packed hi, exact fp32 rescore, softmax, V gather =======
__global__ __launch_bounds__(256) void merge_v(
    const unsigned* __restrict__ Cand, const int* __restrict__ Cnt,
    const float* __restrict__ qg, const float* __restrict__ Kt,
    const float* __restrict__ Vt, float* __restrict__ Og) {
  __shared__ float Wls[128][K9];
  __shared__ int   Ils[128][K9];
  const int tid = threadIdx.x, b = blockIdx.y, qbase = blockIdx.x * 128;

  if (tid < 128) {
    const int n  = qbase + tid;
    const int qi = b * NPIX + n;
    const int c = min(Cnt[qi], CAP);
    const unsigned* cp = Cand + (size_t)qi * CAP;

    // pass 1: top-9 by packed (bf16 score desc, idx asc)
    unsigned tv[K9];
    #pragma unroll
    for (int r = 0; r < K9; ++r) tv[r] = 0u;
    for (int j = 0; j < c; ++j) {
      const unsigned p = cp[j];
      if (p > tv[8]) ins9p(tv, p);
    }
    // threshold key (skip if fewer than 9 candidates)
    unsigned thr16 = 0;
    if (tv[8] != 0u) {
      const unsigned k9 = tv[8] >> 16;
      const unsigned b9 = (k9 & 0x8000u) ? (k9 ^ 0x8000u) : ((~k9) & 0xFFFFu);
      const float f9 = __uint_as_float(b9 << 16);
      thr16 = bfkey(f2bf(f9 - THRM));
    }

    // q-hat row (x8), coalesced strided loads from original [b][d][n]
    float qr[HD];
    #pragma unroll
    for (int d = 0; d < HD; ++d)
      qr[d] = 8.f * qg[((size_t)b * HD + d) * NPIX + n];

    // pass 2: exact fp32 rescore for cands above threshold
    float ev[K9]; int ei[K9];
    #pragma unroll
    for (int r = 0; r < K9; ++r) { ev[r] = -3.4e38f; ei[r] = 0x7fffffff; }
    for (int j = 0; j < c; ++j) {
      const unsigned p = cp[j];
      if ((p >> 16) < thr16) continue;
      const int i = 0xFFFF - (int)(p & 0xFFFFu);
      const float4* kr = reinterpret_cast<const float4*>(Kt + ((size_t)b * NPIX + i) * HD);
      float acc = 0.f;
      #pragma unroll
      for (int u = 0; u < 16; ++u) {
        const float4 kx = kr[u];
        acc = fmaf(qr[u * 4],     kx.x, acc);
        acc = fmaf(qr[u * 4 + 1], kx.y, acc);
        acc = fmaf(qr[u * 4 + 2], kx.z, acc);
        acc = fmaf(qr[u * 4 + 3], kx.w, acc);
      }
      if (acc > ev[8] || (acc == ev[8] && i < ei[8])) ins9t(ev, ei, acc, i);
    }

    const float mmax = ev[0];
    float ex[K9]; float ssum = 0.f;
    #pragma unroll
    for (int r = 0; r < K9; ++r) { ex[r] = expf(ev[r] - mmax); ssum += ex[r]; }
    const float inv = 1.f / ssum;
    #pragma unroll
    for (int r = 0; r < K9; ++r) {
      Wls[tid][r] = ex[r] * inv;
      Ils[tid][r] = (ev[r] > -1e38f) ? ei[r] : 0;   // weight 0 -> safe idx
    }
  }
  __syncthreads();

  // V gather: 2 threads per query, 32 dims each; Vt rows contiguous 256 B
  {
    const int q = tid >> 1, half = tid & 1;
    float o[32];
    #pragma unroll
    for (int c2 = 0; c2 < 32; ++c2) o[c2] = 0.f;
    #pragma unroll
    for (int r = 0; r < K9; ++r) {
      const float wgt = Wls[q][r];
      const int   m   = Ils[q][r];
      const float4* vp = reinterpret_cast<const float4*>(
          Vt + ((size_t)b * NPIX + m) * HD + half * 32);
      #pragma unroll
      for (int c4 = 0; c4 < 8; ++c4) {
        const float4 vv = vp[c4];
        o[c4 * 4]     = fmaf(wgt, vv.x, o[c4 * 4]);
        o[c4 * 4 + 1] = fmaf(wgt, vv.y, o[c4 * 4 + 1]);
        o[c4 * 4 + 2] = fmaf(wgt, vv.z, o[c4 * 4 + 2]);
        o[c4 * 4 + 3] = fmaf(wgt, vv.w, o[c4 * 4 + 3]);
      }
    }
    float* op = Og + (((size_t)b * NPIX) + qbase + q) * HD + half * 32;
    #pragma unroll
    for (int c4 = 0; c4 < 8; ++c4)
      *reinterpret_cast<float4*>(op + c4 * 4) =
        make_float4(o[c4 * 4], o[c4 * 4 + 1], o[c4 * 4 + 2], o[c4 * 4 + 3]);
  }
}

// ================= launch =====================================================
extern "C" void kernel_launch(void* const* d_in, const int* in_sizes, int n_in,
                              void* d_out, int out_size, void* d_ws, size_t ws_size,
                              hipStream_t stream) {
  const float* q = (const float*)d_in[0];
  const float* k = (const float*)d_in[1];
  const float* v = (const float*)d_in[2];
  float* o = (float*)d_out;

  const size_t asz = (size_t)B4 * NPIX * HD;          // 2.36M elems per array
  const int nq = B4 * NPIX;
  ushort_t* Qbf = (ushort_t*)d_ws;                    // 4.72 MB
  ushort_t* Kbf = Qbf + asz;                          // 4.72 MB
  float*    Kt  = (float*)(Kbf + asz);                // 9.44 MB
  float*    Vt  = Kt + asz;                           // 9.44 MB
  float*    Pm  = Vt + asz;                           // 0.29 MB [qi][SSL]
  int*      Ct  = (int*)(Pm + (size_t)nq * SSL);      // 0.15 MB
  unsigned* Cd  = (unsigned*)(Ct + nq);               // 14.2 MB [qi][CAP]

  hipMemsetAsync(Ct, 0, (size_t)nq * sizeof(int), stream);
  prep_kernel<<<dim3(NPIX / 64, B4, 3), 256, 0, stream>>>(q, k, v, Qbf, Kbf, Kt, Vt);
  pass_sample<<<dim3(NPIX / 256, B4, SSL), 256, 0, stream>>>(Qbf, Kbf, Pm);
  pass_gate<<<dim3(NPIX / 256, B4, ZS), 256, 0, stream>>>(Qbf, Kbf, Pm, Ct, Cd);
  merge_v<<<dim3(NPIX / 128, B4), 256, 0, stream>>>(Cd, Ct, q, Kt, Vt, o);
}

// Round 10
// 206.545 us; speedup vs baseline: 1.2062x; 1.2062x over previous
//
#include <hip/hip_runtime.h>
#include <math.h>

#define HD     64
#define NPIX   9216
#define B4     4
#define NQ     (B4 * NPIX)
#define K9     9
#define SSL    8              // sample slices (288 keys each -> keys 0..2303)
#define SKEYS  288
#define ZS     16             // gate key-split
#define KQZ    (NPIX / ZS)    // 576 keys per gate block
#define KTG    64             // gate LDS tile keys
#define NTG    (KQZ / KTG)    // 9
#define KTS    32             // sample LDS tile keys
#define NTS    (SKEYS / KTS)  // 9
#define DGATE  13.0f
#define THRM   4.5f
#define CAP    96

typedef __attribute__((ext_vector_type(8)))  short bf16x8;
typedef __attribute__((ext_vector_type(16))) float f32x16;
typedef unsigned short ushort_t;

__device__ __forceinline__ ushort_t f2bf(float x) {
  unsigned u = __float_as_uint(x);
  unsigned r = (u + 0x7fffu + ((u >> 16) & 1u)) >> 16;   // RNE
  return (ushort_t)r;
}
// monotone bf16-bits -> 16-bit sortable key
__device__ __forceinline__ unsigned bfkey(ushort_t b) {
  return (b & 0x8000u) ? ((~(unsigned)b) & 0xFFFFu) : ((unsigned)b | 0x8000u);
}

// ---- prep: transpose [b][d][n]->[b][n][d]; z=0: Qbf(x8)+Cnt=0; z=1: Kbf+Kt; z=2: Vt
__global__ __launch_bounds__(256) void prep_kernel(
    const float* __restrict__ qg, const float* __restrict__ kg,
    const float* __restrict__ vg,
    ushort_t* __restrict__ Qbf, ushort_t* __restrict__ Kbf,
    float* __restrict__ Kt, float* __restrict__ Vt, int* __restrict__ Cnt) {
  __shared__ float Ts[64][65];
  const int b = blockIdx.y, n0 = blockIdx.x * 64, z = blockIdx.z;
  const float* src = (z == 0) ? qg : (z == 1) ? kg : vg;
  const int tid = threadIdx.x;
  if (z == 0 && b == 0) Cnt[blockIdx.x * 256 + tid] = 0;   // 144*256 = NQ exactly
  #pragma unroll
  for (int i = 0; i < 16; ++i) {
    const int idx = i * 256 + tid, c = idx >> 6, nl = idx & 63;
    Ts[c][nl] = src[((size_t)b * HD + c) * NPIX + n0 + nl];
  }
  __syncthreads();
  if (z == 0) {
    #pragma unroll
    for (int i = 0; i < 16; ++i) {
      const int idx = i * 256 + tid, nl = idx >> 6, d = idx & 63;
      Qbf[((size_t)b * NPIX + n0 + nl) * HD + d] = f2bf(Ts[d][nl] * 8.f);
    }
  } else if (z == 1) {
    #pragma unroll
    for (int i = 0; i < 16; ++i) {
      const int idx = i * 256 + tid, nl = idx >> 6, d = idx & 63;
      const float x = Ts[d][nl];
      const size_t o = ((size_t)b * NPIX + n0 + nl) * HD + d;
      Kbf[o] = f2bf(x); Kt[o] = x;
    }
  } else {
    #pragma unroll
    for (int i = 0; i < 16; ++i) {
      const int idx = i * 256 + tid, nl = idx >> 6, d = idx & 63;
      Vt[((size_t)b * NPIX + n0 + nl) * HD + d] = Ts[d][nl];
    }
  }
}

// ---------------- async global -> LDS (16B per lane, linear dest) ------------
__device__ __forceinline__ void gl_lds16(const void* g, void* l) {
  auto gp = reinterpret_cast<const unsigned int __attribute__((address_space(1)))*>(
      reinterpret_cast<uintptr_t>(g));
  auto lp = reinterpret_cast<unsigned int __attribute__((address_space(3)))*>(
      reinterpret_cast<uintptr_t>(l));
  __builtin_amdgcn_global_load_lds(gp, lp, 16, 0, 0);
}

// ---- sorted-9 insert, float with (val desc, idx asc) tie-break --------------
__device__ __forceinline__ void ins9t(float (&tv)[K9], int (&ti)[K9], float s, int m) {
  float cv = s; int ci = m;
  #pragma unroll
  for (int r = 0; r < K9; ++r) {
    const bool c = (cv > tv[r]) || (cv == tv[r] && ci < ti[r]);
    const float hv = c ? cv : tv[r];  const float lv = c ? tv[r] : cv;
    const int   hk = c ? ci : ti[r];  const int   lk = c ? ti[r] : ci;
    tv[r] = hv; ti[r] = hk; cv = lv; ci = lk;
  }
}
// ---- sorted-9 insert, packed uint -------------------------------------------
__device__ __forceinline__ void ins9p(unsigned (&tv)[K9], unsigned p) {
  unsigned cv = p;
  #pragma unroll
  for (int r = 0; r < K9; ++r) {
    const bool c = cv > tv[r];
    const unsigned hv = c ? cv : tv[r]; const unsigned lv = c ? tv[r] : cv;
    tv[r] = hv; cv = lv;
  }
}

// ==== sample: per-query max over keys [z*288, z*288+288), 32x32 MFMA =========
__global__ __launch_bounds__(256, 4) void pass_sample(
    const ushort_t* __restrict__ Qbf, const ushort_t* __restrict__ Kbf,
    float* __restrict__ Pm) {
  __shared__ __align__(16) char SM[2][4096];   // 32 keys x 128B, double buffer

  const int tid = threadIdx.x;
  const int w = tid >> 6, l = tid & 63;
  const int lq = l & 31, hi = l >> 5, par = l & 7;
  const int b = blockIdx.y, qbase = blockIdx.x * 256, z = blockIdx.z;
  const int kbase = z * KTS * NTS;            // z*288
  const int qw = qbase + w * 64;

  // Q fragments (B operand): col = lane&31 = query, k = (lane>>5)*8 + e
  bf16x8 qf0[4], qf1[4];
  {
    const size_t q0 = ((size_t)b * NPIX + qw + lq) * HD + hi * 8;
    const size_t q1 = q0 + (size_t)32 * HD;
    #pragma unroll
    for (int i = 0; i < 4; ++i) {
      qf0[i] = *reinterpret_cast<const bf16x8*>(Qbf + q0 + i * 16);
      qf1[i] = *reinterpret_cast<const bf16x8*>(Qbf + q1 + i * 16);
    }
  }

  const char* kB = reinterpret_cast<const char*>(Kbf + (size_t)b * NPIX * HD);
  const int sr = tid >> 3, sc = tid & 7;
  const int srcoff = sr * 128 + ((sc ^ (sr & 7)) << 4);
  const int hdst = w * 1024;
  // A-read offsets: row (l&31), block col (i*2+hi)^par
  int oi[4];
  #pragma unroll
  for (int i = 0; i < 4; ++i) oi[i] = lq * 128 + (((i * 2 + hi) ^ par) << 4);

  auto stage = [&](int tile, int nb) {
    const size_t toff = ((size_t)(kbase + tile * KTS)) * 128 + srcoff;
    gl_lds16(kB + toff, SM[nb] + hdst);
  };

  float m0 = -3.4e38f, m1 = -3.4e38f;
  stage(0, 0);
  __syncthreads();

  for (int t = 0; t < NTS; ++t) {
    const int cur = t & 1;
    if (t + 1 < NTS) stage(t + 1, cur ^ 1);
    const char* kt = SM[cur];

    f32x16 a0 = {0.f,0.f,0.f,0.f,0.f,0.f,0.f,0.f,0.f,0.f,0.f,0.f,0.f,0.f,0.f,0.f};
    f32x16 a1 = {0.f,0.f,0.f,0.f,0.f,0.f,0.f,0.f,0.f,0.f,0.f,0.f,0.f,0.f,0.f,0.f};
    #pragma unroll
    for (int i = 0; i < 4; ++i) {
      const bf16x8 av = *reinterpret_cast<const bf16x8*>(kt + oi[i]);
      a0 = __builtin_amdgcn_mfma_f32_32x32x16_bf16(av, qf0[i], a0, 0, 0, 0);
      a1 = __builtin_amdgcn_mfma_f32_32x32x16_bf16(av, qf1[i], a1, 0, 0, 0);
    }
    float s0 = fmaxf(fmaxf(fmaxf(a0[0],a0[1]),fmaxf(a0[2],a0[3])),
               fmaxf(fmaxf(a0[4],a0[5]),fmaxf(a0[6],a0[7])));
    s0 = fmaxf(s0, fmaxf(fmaxf(fmaxf(a0[8],a0[9]),fmaxf(a0[10],a0[11])),
                   fmaxf(fmaxf(a0[12],a0[13]),fmaxf(a0[14],a0[15]))));
    float s1 = fmaxf(fmaxf(fmaxf(a1[0],a1[1]),fmaxf(a1[2],a1[3])),
               fmaxf(fmaxf(a1[4],a1[5]),fmaxf(a1[6],a1[7])));
    s1 = fmaxf(s1, fmaxf(fmaxf(fmaxf(a1[8],a1[9]),fmaxf(a1[10],a1[11])),
                   fmaxf(fmaxf(a1[12],a1[13]),fmaxf(a1[14],a1[15]))));
    m0 = fmaxf(m0, s0);
    m1 = fmaxf(m1, s1);
    __syncthreads();
  }

  // combine the two key-halves (lane l <-> l+32 hold same query)
  m0 = fmaxf(m0, __shfl_xor(m0, 32, 64));
  m1 = fmaxf(m1, __shfl_xor(m1, 32, 64));
  if (l < 32) {
    Pm[(size_t)z * NQ + b * NPIX + qw + l]      = m0;
    Pm[(size_t)z * NQ + b * NPIX + qw + 32 + l] = m1;
  }
}

// ==== gate: 32x32 hi-only scores, tau-seeded per-lane gate, packed append ====
__global__ __launch_bounds__(256, 4) void pass_gate(
    const ushort_t* __restrict__ Qbf, const ushort_t* __restrict__ Kbf,
    const float* __restrict__ Pm,
    int* __restrict__ Cnt, unsigned* __restrict__ Cand) {
  __shared__ __align__(16) char SM[2][8192];   // 64 keys x 128B, double buffer

  const int tid = threadIdx.x;
  const int w = tid >> 6, l = tid & 63;
  const int lq = l & 31, hi = l >> 5, par = l & 7;
  const int b = blockIdx.y, qbase = blockIdx.x * 256, z = blockIdx.z;
  const int kbase = z * KQZ;
  const int qw = qbase + w * 64;

  const int qi0 = b * NPIX + qw + lq;
  const int qi1 = qi0 + 32;

  bf16x8 qf0[4], qf1[4];
  {
    const size_t q0 = (size_t)qi0 * HD + hi * 8;
    const size_t q1 = (size_t)qi1 * HD + hi * 8;
    #pragma unroll
    for (int i = 0; i < 4; ++i) {
      qf0[i] = *reinterpret_cast<const bf16x8*>(Qbf + q0 + i * 16);
      qf1[i] = *reinterpret_cast<const bf16x8*>(Qbf + q1 + i * 16);
    }
  }

  // tau from the 8 sample slices (coalesced [z][qi] loads)
  float tau0 = -3.4e38f, tau1 = -3.4e38f;
  #pragma unroll
  for (int s = 0; s < SSL; ++s) {
    tau0 = fmaxf(tau0, Pm[(size_t)s * NQ + qi0]);
    tau1 = fmaxf(tau1, Pm[(size_t)s * NQ + qi1]);
  }
  float gt0 = tau0 - DGATE, gt1 = tau1 - DGATE;

  const char* kB = reinterpret_cast<const char*>(Kbf + (size_t)b * NPIX * HD);
  const int sr = tid >> 3, sc = tid & 7;
  const int srcoff = sr * 128 + ((sc ^ (sr & 7)) << 4);
  const int hdst = w * 1024;
  int oi[4];
  #pragma unroll
  for (int i = 0; i < 4; ++i) oi[i] = lq * 128 + (((i * 2 + hi) ^ par) << 4);

  auto stage = [&](int tile, int nb) {
    const size_t toff = ((size_t)(kbase + tile * KTG)) * 128 + srcoff;
    gl_lds16(kB + toff, SM[nb] + hdst);
    gl_lds16(kB + toff + 4096, SM[nb] + 4096 + hdst);
  };

  auto emit = [&](float s, int key, int qq) {
    const int slot = atomicAdd(&Cnt[qq], 1);
    if (slot < CAP)
      Cand[(size_t)qq * CAP + slot] =
          (bfkey(f2bf(s)) << 16) | (unsigned)(0xFFFF - key);
  };

  // one chain step: 16 scores for query qq, keys kb+{8*quad + j} (j=0..3)
  auto chain = [&](const f32x16& a, float& gt, int qq, int kb) {
    const float m0q = fmaxf(fmaxf(a[0], a[1]),  fmaxf(a[2], a[3]));
    const float m1q = fmaxf(fmaxf(a[4], a[5]),  fmaxf(a[6], a[7]));
    const float m2q = fmaxf(fmaxf(a[8], a[9]),  fmaxf(a[10], a[11]));
    const float m3q = fmaxf(fmaxf(a[12], a[13]), fmaxf(a[14], a[15]));
    const float s16 = fmaxf(fmaxf(m0q, m1q), fmaxf(m2q, m3q));
    const float old = gt;
    gt = fmaxf(old, s16 - DGATE);
    if (s16 > old) {                         // rare: near-record in this window
      if (m0q > gt) {
        if (a[0] > gt)  emit(a[0],  kb,      qq);
        if (a[1] > gt)  emit(a[1],  kb + 1,  qq);
        if (a[2] > gt)  emit(a[2],  kb + 2,  qq);
        if (a[3] > gt)  emit(a[3],  kb + 3,  qq);
      }
      if (m1q > gt) {
        if (a[4] > gt)  emit(a[4],  kb + 8,  qq);
        if (a[5] > gt)  emit(a[5],  kb + 9,  qq);
        if (a[6] > gt)  emit(a[6],  kb + 10, qq);
        if (a[7] > gt)  emit(a[7],  kb + 11, qq);
      }
      if (m2q > gt) {
        if (a[8] > gt)  emit(a[8],  kb + 16, qq);
        if (a[9] > gt)  emit(a[9],  kb + 17, qq);
        if (a[10] > gt) emit(a[10], kb + 18, qq);
        if (a[11] > gt) emit(a[11], kb + 19, qq);
      }
      if (m3q > gt) {
        if (a[12] > gt) emit(a[12], kb + 24, qq);
        if (a[13] > gt) emit(a[13], kb + 25, qq);
        if (a[14] > gt) emit(a[14], kb + 26, qq);
        if (a[15] > gt) emit(a[15], kb + 27, qq);
      }
    }
  };

  stage(0, 0);
  __syncthreads();

  for (int t = 0; t < NTG; ++t) {
    const int cur = t & 1;
    if (t + 1 < NTG) stage(t + 1, cur ^ 1);
    const char* kt = SM[cur];

    #pragma unroll
    for (int g = 0; g < 2; ++g) {            // two 32-key groups per tile
      const int gbyte = g * 4096;
      f32x16 a0 = {0.f,0.f,0.f,0.f,0.f,0.f,0.f,0.f,0.f,0.f,0.f,0.f,0.f,0.f,0.f,0.f};
      f32x16 a1 = {0.f,0.f,0.f,0.f,0.f,0.f,0.f,0.f,0.f,0.f,0.f,0.f,0.f,0.f,0.f,0.f};
      #pragma unroll
      for (int i = 0; i < 4; ++i) {
        const bf16x8 av = *reinterpret_cast<const bf16x8*>(kt + gbyte + oi[i]);
        a0 = __builtin_amdgcn_mfma_f32_32x32x16_bf16(av, qf0[i], a0, 0, 0, 0);
        a1 = __builtin_amdgcn_mfma_f32_32x32x16_bf16(av, qf1[i], a1, 0, 0, 0);
      }
      const int kb = kbase + t * KTG + g * 32 + 4 * hi;
      chain(a0, gt0, qi0, kb);
      chain(a1, gt1, qi1, kb);
    }
    __syncthreads();
  }
}

// ==== merge: top-9 by packed hi, exact fp32 rescore, softmax, V gather =======
__global__ __launch_bounds__(256) void merge_v(
    const unsigned* __restrict__ Cand, const int* __restrict__ Cnt,
    const float* __restrict__ qg, const float* __restrict__ Kt,
    const float* __restrict__ Vt, float* __restrict__ Og) {
  __shared__ float Wls[128][K9];
  __shared__ int   Ils[128][K9];
  const int tid = threadIdx.x, b = blockIdx.y, qbase = blockIdx.x * 128;

  if (tid < 128) {
    const int n  = qbase + tid;
    const int qi = b * NPIX + n;
    const int c = min(Cnt[qi], CAP);
    const unsigned* cp = Cand + (size_t)qi * CAP;

    // pass 1: top-9 by packed (bf16 score desc, idx asc)
    unsigned tv[K9];
    #pragma unroll
    for (int r = 0; r < K9; ++r) tv[r] = 0u;
    for (int j = 0; j < c; ++j) {
      const unsigned p = cp[j];
      if (p > tv[8]) ins9p(tv, p);
    }
    unsigned thr16 = 0;
    if (tv[8] != 0u) {
      const unsigned k9 = tv[8] >> 16;
      const unsigned b9 = (k9 & 0x8000u) ? (k9 ^ 0x8000u) : ((~k9) & 0xFFFFu);
      const float f9 = __uint_as_float(b9 << 16);
      thr16 = bfkey(f2bf(f9 - THRM));
    }

    // q-hat row (x8), coalesced strided loads from original [b][d][n]
    float qr[HD];
    #pragma unroll
    for (int d = 0; d < HD; ++d)
      qr[d] = 8.f * qg[((size_t)b * HD + d) * NPIX + n];

    // pass 2: exact fp32 rescore for cands above threshold
    float ev[K9]; int ei[K9];
    #pragma unroll
    for (int r = 0; r < K9; ++r) { ev[r] = -3.4e38f; ei[r] = 0x7fffffff; }
    for (int j = 0; j < c; ++j) {
      const unsigned p = cp[j];
      if ((p >> 16) < thr16) continue;
      const int i = 0xFFFF - (int)(p & 0xFFFFu);
      const float4* kr = reinterpret_cast<const float4*>(Kt + ((size_t)b * NPIX + i) * HD);
      float acc = 0.f;
      #pragma unroll
      for (int u = 0; u < 16; ++u) {
        const float4 kx = kr[u];
        acc = fmaf(qr[u * 4],     kx.x, acc);
        acc = fmaf(qr[u * 4 + 1], kx.y, acc);
        acc = fmaf(qr[u * 4 + 2], kx.z, acc);
        acc = fmaf(qr[u * 4 + 3], kx.w, acc);
      }
      if (acc > ev[8] || (acc == ev[8] && i < ei[8])) ins9t(ev, ei, acc, i);
    }

    const float mmax = ev[0];
    float ex[K9]; float ssum = 0.f;
    #pragma unroll
    for (int r = 0; r < K9; ++r) { ex[r] = expf(ev[r] - mmax); ssum += ex[r]; }
    const float inv = 1.f / ssum;
    #pragma unroll
    for (int r = 0; r < K9; ++r) {
      Wls[tid][r] = ex[r] * inv;
      Ils[tid][r] = (ev[r] > -1e38f) ? ei[r] : 0;
    }
  }
  __syncthreads();

  // V gather: 2 threads per query, 32 dims each; Vt rows contiguous 256 B
  {
    const int q = tid >> 1, half = tid & 1;
    float o[32];
    #pragma unroll
    for (int c2 = 0; c2 < 32; ++c2) o[c2] = 0.f;
    #pragma unroll
    for (int r = 0; r < K9; ++r) {
      const float wgt = Wls[q][r];
      const int   m   = Ils[q][r];
      const float4* vp = reinterpret_cast<const float4*>(
          Vt + ((size_t)b * NPIX + m) * HD + half * 32);
      #pragma unroll
      for (int c4 = 0; c4 < 8; ++c4) {
        const float4 vv = vp[c4];
        o[c4 * 4]     = fmaf(wgt, vv.x, o[c4 * 4]);
        o[c4 * 4 + 1] = fmaf(wgt, vv.y, o[c4 * 4 + 1]);
        o[c4 * 4 + 2] = fmaf(wgt, vv.z, o[c4 * 4 + 2]);
        o[c4 * 4 + 3] = fmaf(wgt, vv.w, o[c4 * 4 + 3]);
      }
    }
    float* op = Og + (((size_t)b * NPIX) + qbase + q) * HD + half * 32;
    #pragma unroll
    for (int c4 = 0; c4 < 8; ++c4)
      *reinterpret_cast<float4*>(op + c4 * 4) =
        make_float4(o[c4 * 4], o[c4 * 4 + 1], o[c4 * 4 + 2], o[c4 * 4 + 3]);
  }
}

// ================= launch =====================================================
extern "C" void kernel_launch(void* const* d_in, const int* in_sizes, int n_in,
                              void* d_out, int out_size, void* d_ws, size_t ws_size,
                              hipStream_t stream) {
  const float* q = (const float*)d_in[0];
  const float* k = (const float*)d_in[1];
  const float* v = (const float*)d_in[2];
  float* o = (float*)d_out;

  const size_t asz = (size_t)B4 * NPIX * HD;
  ushort_t* Qbf = (ushort_t*)d_ws;                    // 4.72 MB
  ushort_t* Kbf = Qbf + asz;                          // 4.72 MB
  float*    Kt  = (float*)(Kbf + asz);                // 9.44 MB
  float*    Vt  = Kt + asz;                           // 9.44 MB
  float*    Pm  = Vt + asz;                           // 1.18 MB [SSL][qi]
  int*      Ct  = (int*)(Pm + (size_t)SSL * NQ);      // 0.15 MB
  unsigned* Cd  = (unsigned*)(Ct + NQ);               // 14.2 MB [qi][CAP]

  prep_kernel<<<dim3(NPIX / 64, B4, 3), 256, 0, stream>>>(q, k, v, Qbf, Kbf, Kt, Vt, Ct);
  pass_sample<<<dim3(NPIX / 256, B4, SSL), 256, 0, stream>>>(Qbf, Kbf, Pm);
  pass_gate<<<dim3(NPIX / 256, B4, ZS), 256, 0, stream>>>(Qbf, Kbf, Pm, Ct, Cd);
  merge_v<<<dim3(NPIX / 128, B4), 256, 0, stream>>>(Cd, Ct, q, Kt, Vt, o);
}

// Round 11
// 164.218 us; speedup vs baseline: 1.5171x; 1.2578x over previous
//
#include <hip/hip_runtime.h>
#include <math.h>

#define HD     64
#define NPIX   9216
#define B4     4
#define NQ     (B4 * NPIX)
#define K9     9
#define SSL    8              // sample slices (288 keys each -> keys 0..2303)
#define SKEYS  288
#define ZS     16             // gate key-split
#define KQZ    (NPIX / ZS)    // 576 keys per gate block
#define KTG    64             // gate LDS tile keys
#define NTG    (KQZ / KTG)    // 9
#define KTS    32             // sample LDS tile keys
#define NTS    (SKEYS / KTS)  // 9
#define DGATE  13.0f
#define CAP    96

typedef __attribute__((ext_vector_type(8)))  short bf16x8;
typedef __attribute__((ext_vector_type(16))) float f32x16;
typedef unsigned short ushort_t;

__device__ __forceinline__ ushort_t f2bf(float x) {
  unsigned u = __float_as_uint(x);
  unsigned r = (u + 0x7fffu + ((u >> 16) & 1u)) >> 16;   // RNE
  return (ushort_t)r;
}

// ---- prep: transpose [b][d][n]->[b][n][d]; z=0: Qbf(x8)+Cnt=0; z=1: Kbf+Kt; z=2: Vt
__global__ __launch_bounds__(256) void prep_kernel(
    const float* __restrict__ qg, const float* __restrict__ kg,
    const float* __restrict__ vg,
    ushort_t* __restrict__ Qbf, ushort_t* __restrict__ Kbf,
    float* __restrict__ Kt, float* __restrict__ Vt, int* __restrict__ Cnt) {
  __shared__ float Ts[64][65];
  const int b = blockIdx.y, n0 = blockIdx.x * 64, z = blockIdx.z;
  const float* src = (z == 0) ? qg : (z == 1) ? kg : vg;
  const int tid = threadIdx.x;
  if (z == 0 && b == 0) Cnt[blockIdx.x * 256 + tid] = 0;   // 144*256 = NQ exactly
  #pragma unroll
  for (int i = 0; i < 16; ++i) {
    const int idx = i * 256 + tid, c = idx >> 6, nl = idx & 63;
    Ts[c][nl] = src[((size_t)b * HD + c) * NPIX + n0 + nl];
  }
  __syncthreads();
  if (z == 0) {
    #pragma unroll
    for (int i = 0; i < 16; ++i) {
      const int idx = i * 256 + tid, nl = idx >> 6, d = idx & 63;
      Qbf[((size_t)b * NPIX + n0 + nl) * HD + d] = f2bf(Ts[d][nl] * 8.f);
    }
  } else if (z == 1) {
    #pragma unroll
    for (int i = 0; i < 16; ++i) {
      const int idx = i * 256 + tid, nl = idx >> 6, d = idx & 63;
      const float x = Ts[d][nl];
      const size_t o = ((size_t)b * NPIX + n0 + nl) * HD + d;
      Kbf[o] = f2bf(x); Kt[o] = x;
    }
  } else {
    #pragma unroll
    for (int i = 0; i < 16; ++i) {
      const int idx = i * 256 + tid, nl = idx >> 6, d = idx & 63;
      Vt[((size_t)b * NPIX + n0 + nl) * HD + d] = Ts[d][nl];
    }
  }
}

// ---------------- async global -> LDS (16B per lane, linear dest) ------------
__device__ __forceinline__ void gl_lds16(const void* g, void* l) {
  auto gp = reinterpret_cast<const unsigned int __attribute__((address_space(1)))*>(
      reinterpret_cast<uintptr_t>(g));
  auto lp = reinterpret_cast<unsigned int __attribute__((address_space(3)))*>(
      reinterpret_cast<uintptr_t>(l));
  __builtin_amdgcn_global_load_lds(gp, lp, 16, 0, 0);
}

// ==== sample: per-query max over keys [z*288, z*288+288), 32x32 MFMA =========
__global__ __launch_bounds__(256, 4) void pass_sample(
    const ushort_t* __restrict__ Qbf, const ushort_t* __restrict__ Kbf,
    float* __restrict__ Pm) {
  __shared__ __align__(16) char SM[2][4096];   // 32 keys x 128B, double buffer

  const int tid = threadIdx.x;
  const int w = tid >> 6, l = tid & 63;
  const int lq = l & 31, hi = l >> 5, par = l & 7;
  const int b = blockIdx.y, qbase = blockIdx.x * 256, z = blockIdx.z;
  const int kbase = z * KTS * NTS;            // z*288
  const int qw = qbase + w * 64;

  // Q fragments (B operand): col = lane&31 = query, k = (lane>>5)*8 + e
  bf16x8 qf0[4], qf1[4];
  {
    const size_t q0 = ((size_t)b * NPIX + qw + lq) * HD + hi * 8;
    const size_t q1 = q0 + (size_t)32 * HD;
    #pragma unroll
    for (int i = 0; i < 4; ++i) {
      qf0[i] = *reinterpret_cast<const bf16x8*>(Qbf + q0 + i * 16);
      qf1[i] = *reinterpret_cast<const bf16x8*>(Qbf + q1 + i * 16);
    }
  }

  const char* kB = reinterpret_cast<const char*>(Kbf + (size_t)b * NPIX * HD);
  const int sr = tid >> 3, sc = tid & 7;
  const int srcoff = sr * 128 + ((sc ^ (sr & 7)) << 4);
  const int hdst = w * 1024;
  int oi[4];
  #pragma unroll
  for (int i = 0; i < 4; ++i) oi[i] = lq * 128 + (((i * 2 + hi) ^ par) << 4);

  auto stage = [&](int tile, int nb) {
    const size_t toff = ((size_t)(kbase + tile * KTS)) * 128 + srcoff;
    gl_lds16(kB + toff, SM[nb] + hdst);
  };

  float m0 = -3.4e38f, m1 = -3.4e38f;
  stage(0, 0);
  __syncthreads();

  for (int t = 0; t < NTS; ++t) {
    const int cur = t & 1;
    if (t + 1 < NTS) stage(t + 1, cur ^ 1);
    const char* kt = SM[cur];

    f32x16 a0 = {0.f,0.f,0.f,0.f,0.f,0.f,0.f,0.f,0.f,0.f,0.f,0.f,0.f,0.f,0.f,0.f};
    f32x16 a1 = {0.f,0.f,0.f,0.f,0.f,0.f,0.f,0.f,0.f,0.f,0.f,0.f,0.f,0.f,0.f,0.f};
    #pragma unroll
    for (int i = 0; i < 4; ++i) {
      const bf16x8 av = *reinterpret_cast<const bf16x8*>(kt + oi[i]);
      a0 = __builtin_amdgcn_mfma_f32_32x32x16_bf16(av, qf0[i], a0, 0, 0, 0);
      a1 = __builtin_amdgcn_mfma_f32_32x32x16_bf16(av, qf1[i], a1, 0, 0, 0);
    }
    float s0 = fmaxf(fmaxf(fmaxf(a0[0],a0[1]),fmaxf(a0[2],a0[3])),
               fmaxf(fmaxf(a0[4],a0[5]),fmaxf(a0[6],a0[7])));
    s0 = fmaxf(s0, fmaxf(fmaxf(fmaxf(a0[8],a0[9]),fmaxf(a0[10],a0[11])),
                   fmaxf(fmaxf(a0[12],a0[13]),fmaxf(a0[14],a0[15]))));
    float s1 = fmaxf(fmaxf(fmaxf(a1[0],a1[1]),fmaxf(a1[2],a1[3])),
               fmaxf(fmaxf(a1[4],a1[5]),fmaxf(a1[6],a1[7])));
    s1 = fmaxf(s1, fmaxf(fmaxf(fmaxf(a1[8],a1[9]),fmaxf(a1[10],a1[11])),
                   fmaxf(fmaxf(a1[12],a1[13]),fmaxf(a1[14],a1[15]))));
    m0 = fmaxf(m0, s0);
    m1 = fmaxf(m1, s1);
    __syncthreads();
  }

  m0 = fmaxf(m0, __shfl_xor(m0, 32, 64));
  m1 = fmaxf(m1, __shfl_xor(m1, 32, 64));
  if (l < 32) {
    Pm[(size_t)z * NQ + b * NPIX + qw + l]      = m0;
    Pm[(size_t)z * NQ + b * NPIX + qw + 32 + l] = m1;
  }
}

// ==== gate: 32x32 hi-only scores, tau-seeded per-lane gate, raw idx append ===
__global__ __launch_bounds__(256, 4) void pass_gate(
    const ushort_t* __restrict__ Qbf, const ushort_t* __restrict__ Kbf,
    const float* __restrict__ Pm,
    int* __restrict__ Cnt, unsigned* __restrict__ Cand) {
  __shared__ __align__(16) char SM[2][8192];   // 64 keys x 128B, double buffer

  const int tid = threadIdx.x;
  const int w = tid >> 6, l = tid & 63;
  const int lq = l & 31, hi = l >> 5, par = l & 7;
  const int b = blockIdx.y, qbase = blockIdx.x * 256, z = blockIdx.z;
  const int kbase = z * KQZ;
  const int qw = qbase + w * 64;

  const int qi0 = b * NPIX + qw + lq;
  const int qi1 = qi0 + 32;

  bf16x8 qf0[4], qf1[4];
  {
    const size_t q0 = (size_t)qi0 * HD + hi * 8;
    const size_t q1 = (size_t)qi1 * HD + hi * 8;
    #pragma unroll
    for (int i = 0; i < 4; ++i) {
      qf0[i] = *reinterpret_cast<const bf16x8*>(Qbf + q0 + i * 16);
      qf1[i] = *reinterpret_cast<const bf16x8*>(Qbf + q1 + i * 16);
    }
  }

  float tau0 = -3.4e38f, tau1 = -3.4e38f;
  #pragma unroll
  for (int s = 0; s < SSL; ++s) {
    tau0 = fmaxf(tau0, Pm[(size_t)s * NQ + qi0]);
    tau1 = fmaxf(tau1, Pm[(size_t)s * NQ + qi1]);
  }
  float gt0 = tau0 - DGATE, gt1 = tau1 - DGATE;

  const char* kB = reinterpret_cast<const char*>(Kbf + (size_t)b * NPIX * HD);
  const int sr = tid >> 3, sc = tid & 7;
  const int srcoff = sr * 128 + ((sc ^ (sr & 7)) << 4);
  const int hdst = w * 1024;
  int oi[4];
  #pragma unroll
  for (int i = 0; i < 4; ++i) oi[i] = lq * 128 + (((i * 2 + hi) ^ par) << 4);

  auto stage = [&](int tile, int nb) {
    const size_t toff = ((size_t)(kbase + tile * KTG)) * 128 + srcoff;
    gl_lds16(kB + toff, SM[nb] + hdst);
    gl_lds16(kB + toff + 4096, SM[nb] + 4096 + hdst);
  };

  auto emit = [&](int key, int qq) {
    const int slot = atomicAdd(&Cnt[qq], 1);
    if (slot < CAP) Cand[(size_t)qq * CAP + slot] = (unsigned)key;
  };

  auto chain = [&](const f32x16& a, float& gt, int qq, int kb) {
    const float m0q = fmaxf(fmaxf(a[0], a[1]),  fmaxf(a[2], a[3]));
    const float m1q = fmaxf(fmaxf(a[4], a[5]),  fmaxf(a[6], a[7]));
    const float m2q = fmaxf(fmaxf(a[8], a[9]),  fmaxf(a[10], a[11]));
    const float m3q = fmaxf(fmaxf(a[12], a[13]), fmaxf(a[14], a[15]));
    const float s16 = fmaxf(fmaxf(m0q, m1q), fmaxf(m2q, m3q));
    const float old = gt;
    gt = fmaxf(old, s16 - DGATE);
    if (s16 > old) {                         // rare: near-record in this window
      if (m0q > gt) {
        if (a[0] > gt)  emit(kb,      qq);
        if (a[1] > gt)  emit(kb + 1,  qq);
        if (a[2] > gt)  emit(kb + 2,  qq);
        if (a[3] > gt)  emit(kb + 3,  qq);
      }
      if (m1q > gt) {
        if (a[4] > gt)  emit(kb + 8,  qq);
        if (a[5] > gt)  emit(kb + 9,  qq);
        if (a[6] > gt)  emit(kb + 10, qq);
        if (a[7] > gt)  emit(kb + 11, qq);
      }
      if (m2q > gt) {
        if (a[8] > gt)  emit(kb + 16, qq);
        if (a[9] > gt)  emit(kb + 17, qq);
        if (a[10] > gt) emit(kb + 18, qq);
        if (a[11] > gt) emit(kb + 19, qq);
      }
      if (m3q > gt) {
        if (a[12] > gt) emit(kb + 24, qq);
        if (a[13] > gt) emit(kb + 25, qq);
        if (a[14] > gt) emit(kb + 26, qq);
        if (a[15] > gt) emit(kb + 27, qq);
      }
    }
  };

  stage(0, 0);
  __syncthreads();

  for (int t = 0; t < NTG; ++t) {
    const int cur = t & 1;
    if (t + 1 < NTG) stage(t + 1, cur ^ 1);
    const char* kt = SM[cur];

    #pragma unroll
    for (int g = 0; g < 2; ++g) {
      const int gbyte = g * 4096;
      f32x16 a0 = {0.f,0.f,0.f,0.f,0.f,0.f,0.f,0.f,0.f,0.f,0.f,0.f,0.f,0.f,0.f,0.f};
      f32x16 a1 = {0.f,0.f,0.f,0.f,0.f,0.f,0.f,0.f,0.f,0.f,0.f,0.f,0.f,0.f,0.f,0.f};
      #pragma unroll
      for (int i = 0; i < 4; ++i) {
        const bf16x8 av = *reinterpret_cast<const bf16x8*>(kt + gbyte + oi[i]);
        a0 = __builtin_amdgcn_mfma_f32_32x32x16_bf16(av, qf0[i], a0, 0, 0, 0);
        a1 = __builtin_amdgcn_mfma_f32_32x32x16_bf16(av, qf1[i], a1, 0, 0, 0);
      }
      const int kb = kbase + t * KTG + g * 32 + 4 * hi;
      chain(a0, gt0, qi0, kb);
      chain(a1, gt1, qi1, kb);
    }
    __syncthreads();
  }
}

// ==== merge: wave-parallel exact rescore + top-9 extraction + V gather =======
// 2 queries per wave (32 lanes each), 8 queries per block.
__global__ __launch_bounds__(256) void merge_v(
    const unsigned* __restrict__ Cand, const int* __restrict__ Cnt,
    const float* __restrict__ qg, const float* __restrict__ Kt,
    const float* __restrict__ Vt, float* __restrict__ Og) {
  __shared__ float Qs[8][HD];
  const int tid = threadIdx.x, b = blockIdx.y;
  const int nbase = blockIdx.x * 8;

  // stage the 8 q-rows (x8 scale) into LDS
  {
    const int ql = tid >> 5, d0 = (tid & 31) * 2;
    const int n = nbase + ql;
    Qs[ql][d0]     = 8.f * qg[((size_t)b * HD + d0) * NPIX + n];
    Qs[ql][d0 + 1] = 8.f * qg[((size_t)b * HD + d0 + 1) * NPIX + n];
  }
  __syncthreads();

  const int wid = tid >> 6, lane = tid & 63;
  const int half = lane >> 5, l32 = lane & 31;
  const int ql = wid * 2 + half;             // local query 0..7
  const int n  = nbase + ql;
  const int qi = b * NPIX + n;
  const int c  = min(Cnt[qi], CAP);

  // rescore candidates: lane j handles slots j, j+32, j+64 (exact fp32 dot)
  unsigned long long p[3] = {0ull, 0ull, 0ull};
  #pragma unroll
  for (int r = 0; r < 3; ++r) {
    const int j = r * 32 + l32;
    if (j < c) {
      const int idx = (int)Cand[(size_t)qi * CAP + j];
      const float4* kr = reinterpret_cast<const float4*>(
          Kt + ((size_t)b * NPIX + idx) * HD);
      float acc = 0.f;
      #pragma unroll
      for (int u = 0; u < 16; ++u) {
        const float4 qx = *reinterpret_cast<const float4*>(&Qs[ql][u * 4]);
        const float4 kx = kr[u];
        acc = fmaf(qx.x, kx.x, acc); acc = fmaf(qx.y, kx.y, acc);
        acc = fmaf(qx.z, kx.z, acc); acc = fmaf(qx.w, kx.w, acc);
      }
      unsigned ub = __float_as_uint(acc);
      ub = (ub & 0x80000000u) ? ~ub : (ub | 0x80000000u);   // sortable fp32
      p[r] = ((unsigned long long)ub << 14) |
             (unsigned long long)(unsigned)(0x3FFF - idx);  // tie: lower idx wins
    }
  }

  // 9 extraction rounds: group-max over 32 lanes, remove winner
  float mv[K9]; int mi[K9];
  #pragma unroll
  for (int r = 0; r < K9; ++r) {
    unsigned long long bst = p[0] > p[1] ? p[0] : p[1];
    bst = bst > p[2] ? bst : p[2];
    #pragma unroll
    for (int m = 1; m < 32; m <<= 1) {
      const unsigned long long o = __shfl_xor(bst, m, 32);
      bst = (o > bst) ? o : bst;
    }
    if (bst != 0ull) {
      #pragma unroll
      for (int s = 0; s < 3; ++s) if (p[s] == bst) p[s] = 0ull;
      const int idx = 0x3FFF - (int)(bst & 0x3FFFull);
      unsigned ub = (unsigned)(bst >> 14);
      ub = (ub & 0x80000000u) ? (ub ^ 0x80000000u) : ~ub;
      mv[r] = __uint_as_float(ub);
      mi[r] = idx;
    } else {
      mv[r] = -3.4e38f; mi[r] = 0;
    }
  }

  // softmax (descending order -> mv[0] is the max) + coalesced V gather
  const float mmax = mv[0];
  float wr[K9]; float wsum = 0.f;
  #pragma unroll
  for (int r = 0; r < K9; ++r) { wr[r] = expf(mv[r] - mmax); wsum += wr[r]; }
  const float inv = 1.f / wsum;

  float2 o2 = make_float2(0.f, 0.f);
  #pragma unroll
  for (int r = 0; r < K9; ++r) {
    const float w = wr[r] * inv;
    const float2 v2 = *reinterpret_cast<const float2*>(
        Vt + ((size_t)b * NPIX + mi[r]) * HD + l32 * 2);
    o2.x = fmaf(w, v2.x, o2.x);
    o2.y = fmaf(w, v2.y, o2.y);
  }
  *reinterpret_cast<float2*>(Og + ((size_t)b * NPIX + n) * HD + l32 * 2) = o2;
}

// ================= launch =====================================================
extern "C" void kernel_launch(void* const* d_in, const int* in_sizes, int n_in,
                              void* d_out, int out_size, void* d_ws, size_t ws_size,
                              hipStream_t stream) {
  const float* q = (const float*)d_in[0];
  const float* k = (const float*)d_in[1];
  const float* v = (const float*)d_in[2];
  float* o = (float*)d_out;

  const size_t asz = (size_t)B4 * NPIX * HD;
  ushort_t* Qbf = (ushort_t*)d_ws;                    // 4.72 MB
  ushort_t* Kbf = Qbf + asz;                          // 4.72 MB
  float*    Kt  = (float*)(Kbf + asz);                // 9.44 MB
  float*    Vt  = Kt + asz;                           // 9.44 MB
  float*    Pm  = Vt + asz;                           // 1.18 MB [SSL][qi]
  int*      Ct  = (int*)(Pm + (size_t)SSL * NQ);      // 0.15 MB
  unsigned* Cd  = (unsigned*)(Ct + NQ);               // 14.2 MB [qi][CAP]

  prep_kernel<<<dim3(NPIX / 64, B4, 3), 256, 0, stream>>>(q, k, v, Qbf, Kbf, Kt, Vt, Ct);
  pass_sample<<<dim3(NPIX / 256, B4, SSL), 256, 0, stream>>>(Qbf, Kbf, Pm);
  pass_gate<<<dim3(NPIX / 256, B4, ZS), 256, 0, stream>>>(Qbf, Kbf, Pm, Ct, Cd);
  merge_v<<<dim3(NPIX / 8, B4), 256, 0, stream>>>(Cd, Ct, q, Kt, Vt, o);
}

// Round 12
// 123.994 us; speedup vs baseline: 2.0092x; 1.3244x over previous
//
#include <hip/hip_runtime.h>
#include <math.h>

#define HD     64
#define NPIX   9216
#define B4     4
#define NQ     (B4 * NPIX)
#define K9     9
#define SSL    8              // sample slices (288 keys each -> keys 0..2303)
#define ZS     16             // gate key-split
#define KQZ    (NPIX / ZS)    // 576 keys per gate block
#define KTG    64             // gate LDS tile keys
#define NTG    (KQZ / KTG)    // 9
#define KTS    32             // sample LDS tile keys
#define NTS    9              // 288 keys per sample slice
#define DGATE  13.0f
#define CAP    96

typedef __attribute__((ext_vector_type(8)))  short bf16x8;
typedef __attribute__((ext_vector_type(16))) float f32x16;
typedef unsigned short ushort_t;
typedef unsigned long long u64;

__device__ __forceinline__ ushort_t f2bf(float x) {
  unsigned u = __float_as_uint(x);
  unsigned r = (u + 0x7fffu + ((u >> 16) & 1u)) >> 16;   // RNE
  return (ushort_t)r;
}

// ---- prep: transpose [b][d][n]->[b][n][d]; z=0: Qbf(x8)+Cnt=0; z=1: Kbf+Kt; z=2: Vt
__global__ __launch_bounds__(256) void prep_kernel(
    const float* __restrict__ qg, const float* __restrict__ kg,
    const float* __restrict__ vg,
    ushort_t* __restrict__ Qbf, ushort_t* __restrict__ Kbf,
    float* __restrict__ Kt, float* __restrict__ Vt, int* __restrict__ Cnt) {
  __shared__ float Ts[64][65];
  const int b = blockIdx.y, n0 = blockIdx.x * 64, z = blockIdx.z;
  const float* src = (z == 0) ? qg : (z == 1) ? kg : vg;
  const int tid = threadIdx.x;
  if (z == 0 && b == 0) Cnt[blockIdx.x * 256 + tid] = 0;   // 144*256 = NQ exactly
  #pragma unroll
  for (int i = 0; i < 16; ++i) {
    const int idx = i * 256 + tid, c = idx >> 6, nl = idx & 63;
    Ts[c][nl] = src[((size_t)b * HD + c) * NPIX + n0 + nl];
  }
  __syncthreads();
  if (z == 0) {
    #pragma unroll
    for (int i = 0; i < 16; ++i) {
      const int idx = i * 256 + tid, nl = idx >> 6, d = idx & 63;
      Qbf[((size_t)b * NPIX + n0 + nl) * HD + d] = f2bf(Ts[d][nl] * 8.f);
    }
  } else if (z == 1) {
    #pragma unroll
    for (int i = 0; i < 16; ++i) {
      const int idx = i * 256 + tid, nl = idx >> 6, d = idx & 63;
      const float x = Ts[d][nl];
      const size_t o = ((size_t)b * NPIX + n0 + nl) * HD + d;
      Kbf[o] = f2bf(x); Kt[o] = x;
    }
  } else {
    #pragma unroll
    for (int i = 0; i < 16; ++i) {
      const int idx = i * 256 + tid, nl = idx >> 6, d = idx & 63;
      Vt[((size_t)b * NPIX + n0 + nl) * HD + d] = Ts[d][nl];
    }
  }
}

// ---------------- async global -> LDS (16B per lane, linear dest) ------------
__device__ __forceinline__ void gl_lds16(const void* g, void* l) {
  auto gp = reinterpret_cast<const unsigned int __attribute__((address_space(1)))*>(
      reinterpret_cast<uintptr_t>(g));
  auto lp = reinterpret_cast<unsigned int __attribute__((address_space(3)))*>(
      reinterpret_cast<uintptr_t>(l));
  __builtin_amdgcn_global_load_lds(gp, lp, 16, 0, 0);
}

// ==== sample: per-query max over keys [z*288, z*288+288), 32x32 MFMA =========
__global__ __launch_bounds__(256, 4) void pass_sample(
    const ushort_t* __restrict__ Qbf, const ushort_t* __restrict__ Kbf,
    float* __restrict__ Pm) {
  __shared__ __align__(16) char SM[2][4096];   // 32 keys x 128B, double buffer

  const int tid = threadIdx.x;
  const int w = tid >> 6, l = tid & 63;
  const int lq = l & 31, hi = l >> 5, par = l & 7;
  const int b = blockIdx.y, qbase = blockIdx.x * 256, z = blockIdx.z;
  const int kbase = z * KTS * NTS;            // z*288
  const int qw = qbase + w * 64;

  // Q fragments (B operand): col = lane&31 = query, k = (lane>>5)*8 + e
  bf16x8 qf0[4], qf1[4];
  {
    const size_t q0 = ((size_t)b * NPIX + qw + lq) * HD + hi * 8;
    const size_t q1 = q0 + (size_t)32 * HD;
    #pragma unroll
    for (int i = 0; i < 4; ++i) {
      qf0[i] = *reinterpret_cast<const bf16x8*>(Qbf + q0 + i * 16);
      qf1[i] = *reinterpret_cast<const bf16x8*>(Qbf + q1 + i * 16);
    }
  }

  const char* kB = reinterpret_cast<const char*>(Kbf + (size_t)b * NPIX * HD);
  const int sr = tid >> 3, sc = tid & 7;
  const int srcoff = sr * 128 + ((sc ^ (sr & 7)) << 4);
  const int hdst = w * 1024;
  int oi[4];
  #pragma unroll
  for (int i = 0; i < 4; ++i) oi[i] = lq * 128 + (((i * 2 + hi) ^ par) << 4);

  auto stage = [&](int tile, int nb) {
    const size_t toff = ((size_t)(kbase + tile * KTS)) * 128 + srcoff;
    gl_lds16(kB + toff, SM[nb] + hdst);
  };

  float m0 = -3.4e38f, m1 = -3.4e38f;
  stage(0, 0);
  __syncthreads();

  for (int t = 0; t < NTS; ++t) {
    const int cur = t & 1;
    if (t + 1 < NTS) stage(t + 1, cur ^ 1);
    const char* kt = SM[cur];

    f32x16 a0 = {0.f,0.f,0.f,0.f,0.f,0.f,0.f,0.f,0.f,0.f,0.f,0.f,0.f,0.f,0.f,0.f};
    f32x16 a1 = {0.f,0.f,0.f,0.f,0.f,0.f,0.f,0.f,0.f,0.f,0.f,0.f,0.f,0.f,0.f,0.f};
    #pragma unroll
    for (int i = 0; i < 4; ++i) {
      const bf16x8 av = *reinterpret_cast<const bf16x8*>(kt + oi[i]);
      a0 = __builtin_amdgcn_mfma_f32_32x32x16_bf16(av, qf0[i], a0, 0, 0, 0);
      a1 = __builtin_amdgcn_mfma_f32_32x32x16_bf16(av, qf1[i], a1, 0, 0, 0);
    }
    float s0 = fmaxf(fmaxf(fmaxf(a0[0],a0[1]),fmaxf(a0[2],a0[3])),
               fmaxf(fmaxf(a0[4],a0[5]),fmaxf(a0[6],a0[7])));
    s0 = fmaxf(s0, fmaxf(fmaxf(fmaxf(a0[8],a0[9]),fmaxf(a0[10],a0[11])),
                   fmaxf(fmaxf(a0[12],a0[13]),fmaxf(a0[14],a0[15]))));
    float s1 = fmaxf(fmaxf(fmaxf(a1[0],a1[1]),fmaxf(a1[2],a1[3])),
               fmaxf(fmaxf(a1[4],a1[5]),fmaxf(a1[6],a1[7])));
    s1 = fmaxf(s1, fmaxf(fmaxf(fmaxf(a1[8],a1[9]),fmaxf(a1[10],a1[11])),
                   fmaxf(fmaxf(a1[12],a1[13]),fmaxf(a1[14],a1[15]))));
    m0 = fmaxf(m0, s0);
    m1 = fmaxf(m1, s1);
    __syncthreads();
  }

  m0 = fmaxf(m0, __shfl_xor(m0, 32, 64));
  m1 = fmaxf(m1, __shfl_xor(m1, 32, 64));
  if (l < 32) {
    Pm[(size_t)z * NQ + b * NPIX + qw + l]      = m0;
    Pm[(size_t)z * NQ + b * NPIX + qw + 32 + l] = m1;
  }
}

// ---- per-lane candidate shift-register buffer (8 x 16-bit local keys) -------
struct LB { u64 lo, hi; int cnt; };

__device__ __forceinline__ void flushLB(LB& b, int qi, int kbase,
                                        int* __restrict__ Cnt,
                                        unsigned* __restrict__ Cand) {
  if (b.cnt == 0) return;
  const int slot = atomicAdd(&Cnt[qi], b.cnt);
  for (int j = 0; j < b.cnt; ++j) {
    const int sh = 16 * j;
    const unsigned key = (sh < 64) ? (unsigned)((b.lo >> sh) & 0xFFFFull)
                                   : (unsigned)((b.hi >> (sh - 64)) & 0xFFFFull);
    if (slot + j < CAP)
      Cand[(size_t)qi * CAP + slot + j] = (unsigned)(kbase + (int)key);
  }
  b.lo = 0ull; b.hi = 0ull; b.cnt = 0;
}

__device__ __forceinline__ void pushLB(LB& b, unsigned key10, int qi, int kbase,
                                       int* __restrict__ Cnt,
                                       unsigned* __restrict__ Cand) {
  b.hi = (b.hi << 16) | (b.lo >> 48);
  b.lo = (b.lo << 16) | (u64)key10;
  if (++b.cnt == 8) flushLB(b, qi, kbase, Cnt, Cand);   // rare slow path
}

// ==== gate: 32x32 hi-only scores, register-buffered emits, end-of-kernel flush
__global__ __launch_bounds__(256, 4) void pass_gate(
    const ushort_t* __restrict__ Qbf, const ushort_t* __restrict__ Kbf,
    const float* __restrict__ Pm,
    int* __restrict__ Cnt, unsigned* __restrict__ Cand) {
  __shared__ __align__(16) char SM[2][8192];   // 64 keys x 128B, double buffer

  const int tid = threadIdx.x;
  const int w = tid >> 6, l = tid & 63;
  const int lq = l & 31, hi = l >> 5, par = l & 7;
  const int b = blockIdx.y, qbase = blockIdx.x * 256, z = blockIdx.z;
  const int kbase = z * KQZ;
  const int qw = qbase + w * 64;

  const int qi0 = b * NPIX + qw + lq;
  const int qi1 = qi0 + 32;

  bf16x8 qf0[4], qf1[4];
  {
    const size_t q0 = (size_t)qi0 * HD + hi * 8;
    const size_t q1 = (size_t)qi1 * HD + hi * 8;
    #pragma unroll
    for (int i = 0; i < 4; ++i) {
      qf0[i] = *reinterpret_cast<const bf16x8*>(Qbf + q0 + i * 16);
      qf1[i] = *reinterpret_cast<const bf16x8*>(Qbf + q1 + i * 16);
    }
  }

  float tau0 = -3.4e38f, tau1 = -3.4e38f;
  #pragma unroll
  for (int s = 0; s < SSL; ++s) {
    tau0 = fmaxf(tau0, Pm[(size_t)s * NQ + qi0]);
    tau1 = fmaxf(tau1, Pm[(size_t)s * NQ + qi1]);
  }
  float gt0 = tau0 - DGATE, gt1 = tau1 - DGATE;

  const char* kB = reinterpret_cast<const char*>(Kbf + (size_t)b * NPIX * HD);
  const int sr = tid >> 3, sc = tid & 7;
  const int srcoff = sr * 128 + ((sc ^ (sr & 7)) << 4);
  const int hdst = w * 1024;
  int oi[4];
  #pragma unroll
  for (int i = 0; i < 4; ++i) oi[i] = lq * 128 + (((i * 2 + hi) ^ par) << 4);

  auto stage = [&](int tile, int nb) {
    const size_t toff = ((size_t)(kbase + tile * KTG)) * 128 + srcoff;
    gl_lds16(kB + toff, SM[nb] + hdst);
    gl_lds16(kB + toff + 4096, SM[nb] + 4096 + hdst);
  };

  LB lb0 = {0ull, 0ull, 0}, lb1 = {0ull, 0ull, 0};

  // chain step: 16 scores for one query; kb is the LOCAL key base (in-slice)
  auto chain = [&](const f32x16& a, float& gt, LB& lb, int qi, int kb) {
    const float t0 = fmaxf(fmaxf(a[0],  a[1]),  a[2]);
    const float t1 = fmaxf(fmaxf(a[3],  a[4]),  a[5]);
    const float t2 = fmaxf(fmaxf(a[6],  a[7]),  a[8]);
    const float t3 = fmaxf(fmaxf(a[9],  a[10]), a[11]);
    const float t4 = fmaxf(fmaxf(a[12], a[13]), a[14]);
    const float s16 = fmaxf(fmaxf(fmaxf(t0, t1), t2),
                            fmaxf(fmaxf(t3, t4), a[15]));
    const float old = gt;
    gt = fmaxf(old, s16 - DGATE);
    if (s16 > old) {                     // rare: near-record in this window
      #pragma unroll
      for (int e = 0; e < 16; ++e) {
        const int off = (e >> 2) * 8 + (e & 3);   // reg -> key offset
        if (a[e] > gt) pushLB(lb, (unsigned)(kb + off), qi, kbase, Cnt, Cand);
      }
    }
  };

  stage(0, 0);
  __syncthreads();

  for (int t = 0; t < NTG; ++t) {
    const int cur = t & 1;
    if (t + 1 < NTG) stage(t + 1, cur ^ 1);
    const char* kt = SM[cur];

    #pragma unroll
    for (int g = 0; g < 2; ++g) {
      const int gbyte = g * 4096;
      f32x16 a0 = {0.f,0.f,0.f,0.f,0.f,0.f,0.f,0.f,0.f,0.f,0.f,0.f,0.f,0.f,0.f,0.f};
      f32x16 a1 = {0.f,0.f,0.f,0.f,0.f,0.f,0.f,0.f,0.f,0.f,0.f,0.f,0.f,0.f,0.f,0.f};
      #pragma unroll
      for (int i = 0; i < 4; ++i) {
        const bf16x8 av = *reinterpret_cast<const bf16x8*>(kt + gbyte + oi[i]);
        a0 = __builtin_amdgcn_mfma_f32_32x32x16_bf16(av, qf0[i], a0, 0, 0, 0);
        a1 = __builtin_amdgcn_mfma_f32_32x32x16_bf16(av, qf1[i], a1, 0, 0, 0);
      }
      const int kb = t * KTG + g * 32 + 4 * hi;   // local (in-slice) key base
      chain(a0, gt0, lb0, qi0, kb);
      chain(a1, gt1, lb1, qi1, kb);
    }
    __syncthreads();
  }

  flushLB(lb0, qi0, kbase, Cnt, Cand);
  flushLB(lb1, qi1, kbase, Cnt, Cand);
}

// ==== merge: wave-parallel exact rescore + top-9 extraction + V gather =======
// 2 queries per wave (32 lanes each), 8 queries per block.
__global__ __launch_bounds__(256) void merge_v(
    const unsigned* __restrict__ Cand, const int* __restrict__ Cnt,
    const float* __restrict__ qg, const float* __restrict__ Kt,
    const float* __restrict__ Vt, float* __restrict__ Og) {
  __shared__ float Qs[8][HD];
  const int tid = threadIdx.x, b = blockIdx.y;
  const int nbase = blockIdx.x * 8;

  {
    const int ql = tid >> 5, d0 = (tid & 31) * 2;
    const int n = nbase + ql;
    Qs[ql][d0]     = 8.f * qg[((size_t)b * HD + d0) * NPIX + n];
    Qs[ql][d0 + 1] = 8.f * qg[((size_t)b * HD + d0 + 1) * NPIX + n];
  }
  __syncthreads();

  const int wid = tid >> 6, lane = tid & 63;
  const int half = lane >> 5, l32 = lane & 31;
  const int ql = wid * 2 + half;
  const int n  = nbase + ql;
  const int qi = b * NPIX + n;
  const int c  = min(Cnt[qi], CAP);

  u64 p[3] = {0ull, 0ull, 0ull};
  #pragma unroll
  for (int r = 0; r < 3; ++r) {
    const int j = r * 32 + l32;
    if (j < c) {
      const int idx = (int)Cand[(size_t)qi * CAP + j];
      const float4* kr = reinterpret_cast<const float4*>(
          Kt + ((size_t)b * NPIX + idx) * HD);
      float acc = 0.f;
      #pragma unroll
      for (int u = 0; u < 16; ++u) {
        const float4 qx = *reinterpret_cast<const float4*>(&Qs[ql][u * 4]);
        const float4 kx = kr[u];
        acc = fmaf(qx.x, kx.x, acc); acc = fmaf(qx.y, kx.y, acc);
        acc = fmaf(qx.z, kx.z, acc); acc = fmaf(qx.w, kx.w, acc);
      }
      unsigned ub = __float_as_uint(acc);
      ub = (ub & 0x80000000u) ? ~ub : (ub | 0x80000000u);
      p[r] = ((u64)ub << 14) | (u64)(unsigned)(0x3FFF - idx);
    }
  }

  float mv[K9]; int mi[K9];
  #pragma unroll
  for (int r = 0; r < K9; ++r) {
    u64 bst = p[0] > p[1] ? p[0] : p[1];
    bst = bst > p[2] ? bst : p[2];
    #pragma unroll
    for (int m = 1; m < 32; m <<= 1) {
      const u64 o = __shfl_xor(bst, m, 32);
      bst = (o > bst) ? o : bst;
    }
    if (bst != 0ull) {
      #pragma unroll
      for (int s = 0; s < 3; ++s) if (p[s] == bst) p[s] = 0ull;
      const int idx = 0x3FFF - (int)(bst & 0x3FFFull);
      unsigned ub = (unsigned)(bst >> 14);
      ub = (ub & 0x80000000u) ? (ub ^ 0x80000000u) : ~ub;
      mv[r] = __uint_as_float(ub);
      mi[r] = idx;
    } else {
      mv[r] = -3.4e38f; mi[r] = 0;
    }
  }

  const float mmax = mv[0];
  float wr[K9]; float wsum = 0.f;
  #pragma unroll
  for (int r = 0; r < K9; ++r) { wr[r] = expf(mv[r] - mmax); wsum += wr[r]; }
  const float inv = 1.f / wsum;

  float2 o2 = make_float2(0.f, 0.f);
  #pragma unroll
  for (int r = 0; r < K9; ++r) {
    const float w2 = wr[r] * inv;
    const float2 v2 = *reinterpret_cast<const float2*>(
        Vt + ((size_t)b * NPIX + mi[r]) * HD + l32 * 2);
    o2.x = fmaf(w2, v2.x, o2.x);
    o2.y = fmaf(w2, v2.y, o2.y);
  }
  *reinterpret_cast<float2*>(Og + ((size_t)b * NPIX + n) * HD + l32 * 2) = o2;
}

// ================= launch =====================================================
extern "C" void kernel_launch(void* const* d_in, const int* in_sizes, int n_in,
                              void* d_out, int out_size, void* d_ws, size_t ws_size,
                              hipStream_t stream) {
  const float* q = (const float*)d_in[0];
  const float* k = (const float*)d_in[1];
  const float* v = (const float*)d_in[2];
  float* o = (float*)d_out;

  const size_t asz = (size_t)B4 * NPIX * HD;
  ushort_t* Qbf = (ushort_t*)d_ws;                    // 4.72 MB
  ushort_t* Kbf = Qbf + asz;                          // 4.72 MB
  float*    Kt  = (float*)(Kbf + asz);                // 9.44 MB
  float*    Vt  = Kt + asz;                           // 9.44 MB
  float*    Pm  = Vt + asz;                           // 1.18 MB [SSL][qi]
  int*      Ct  = (int*)(Pm + (size_t)SSL * NQ);      // 0.15 MB
  unsigned* Cd  = (unsigned*)(Ct + NQ);               // 14.2 MB [qi][CAP]

  prep_kernel<<<dim3(NPIX / 64, B4, 3), 256, 0, stream>>>(q, k, v, Qbf, Kbf, Kt, Vt, Ct);
  pass_sample<<<dim3(NPIX / 256, B4, SSL), 256, 0, stream>>>(Qbf, Kbf, Pm);
  pass_gate<<<dim3(NPIX / 256, B4, ZS), 256, 0, stream>>>(Qbf, Kbf, Pm, Ct, Cd);
  merge_v<<<dim3(NPIX / 8, B4), 256, 0, stream>>>(Cd, Ct, q, Kt, Vt, o);
}